// Round 13
// baseline (526.783 us; speedup 1.0000x reference)
//
#include <hip/hip_runtime.h>
#include <hip/hip_bf16.h>
#include <stdint.h>

#define VOCAB 50257
#define WD 300
#define KP1 320              // word dim padded to mult of 32
#define MP 50432             // vocab rows padded: 394*128

using bf16 = __hip_bfloat16;
typedef __attribute__((ext_vector_type(4))) float f32x4;
typedef __attribute__((ext_vector_type(8))) short bf16x8;

// async global->LDS, 16B per lane; LDS dest = wave-uniform base + lane*16
__device__ __forceinline__ void async_load16(const void* g, void* l) {
    __builtin_amdgcn_global_load_lds(
        (const __attribute__((address_space(1))) uint32_t*)(uintptr_t)g,
        (__attribute__((address_space(3))) uint32_t*)l, 16, 0, 0);
}

// ---------- prep: weights + b4 + zeros + barrier-state zero ------------------
__global__ void prep_w(const float* __restrict__ W1, const float* __restrict__ W2,
                       const float* __restrict__ b2,
                       bf16* __restrict__ w1t, bf16* __restrict__ w2t,
                       bf16* __restrict__ w2b, float* __restrict__ b4,
                       float* __restrict__ zbuf, int* __restrict__ bar) {
    if (blockIdx.x == 1344) {           // bias block: b4 = b2@(A+B) + b2
        __shared__ float b2s[256];
        int n = threadIdx.x;
        b2s[n] = b2[n];
        zbuf[n] = 0.0f;
        if (n < 8) bar[n] = 0;          // grid-barrier state (cnt, gen)
        __syncthreads();
        float acc = b2s[n];
        #pragma unroll 8
        for (int k = 0; k < 256; ++k)
            acc += b2s[k] * (W2[k * 256 + n] + W2[(k + 256) * 256 + n]);
        b4[n] = acc;
        return;
    }
    int idx = blockIdx.x * 256 + threadIdx.x;
    if (idx < 256 * KP1) {                              // w1t = W1^T (zero-pad)
        int n = idx / KP1;
        int k = idx - n * KP1;
        w1t[idx] = __float2bfloat16(k < WD ? W1[k * 256 + n] : 0.0f);
    } else if (idx < 256 * KP1 + 131072) {              // w2t = W2^T
        int j = idx - 256 * KP1;
        int n = j >> 9, k = j & 511;
        w2t[j] = __float2bfloat16(W2[k * 256 + n]);
    } else {                                            // w2b = cast(W2)
        int j = idx - 256 * KP1 - 131072;
        w2b[j] = __float2bfloat16(W2[j]);
    }
}

// ---------- software grid barrier (all blocks co-resident by construction) ---
__device__ __forceinline__ void gbar(int* cnt, int* gen, int nb) {
    __syncthreads();
    if (threadIdx.x == 0) {
        __threadfence();                        // release: my writes visible
        int g = atomicAdd(gen, 0);              // current generation
        int a = atomicAdd(cnt, 1);
        if (a == nb - 1) {
            atomicExch(cnt, 0);
            __threadfence();
            atomicAdd(gen, 1);                  // release all
        } else {
            int spins = 0;
            while (atomicAdd(gen, 0) == g) {
                __builtin_amdgcn_s_sleep(16);
                if (++spins > (1 << 18)) break; // bailout: fail loud, not hang
            }
            __threadfence();                    // acquire
        }
    }
    __syncthreads();
}

// ---------- unified 128-row x 256-col tile (8 waves: 2 rg x 4 cgr) -----------
// AMODE 0: A bf16, row stride As elems; 3-stage PIPE (verified R8/R10/R12)
// AMODE 1: A row r = concat4(proj[ids4[m0+r]]), K = 1024; 3-stage PIPE
// AMODE 2: A fp32 rows stride WD (emb, clamped); single-stage 2-barrier
template <int AMODE, bool OUT_F32>
__device__ __forceinline__ void tile_gemm(
    char* smem, const void* Av, const int* ids,
    const bf16* BT, int Bstr, const float* bias,
    void* C, int Cs, int coff, int K, int As, int m0,
    const float* zbuf)
{
    constexpr int ASZ = (AMODE == 2) ? 16384 : 8192;
    constexpr int BSZ = 16384, STAGE = ASZ + BSZ;

    const int t = threadIdx.x, w = t >> 6, lane = t & 63;
    const int rg = w >> 2, cgr = w & 3, mi = lane & 15, q = lane >> 4;
    const bf16* Ab = (const bf16*)Av;

    int4 idq = {0, 0, 0, 0};
    if constexpr (AMODE == 1) idq = ((const int4*)ids)[m0 + (t >> 2)];

    auto stage = [&](int ke, int buf) {
        char* Asm = smem + buf * STAGE;
        char* Bsm = Asm + ASZ;
        if constexpr (AMODE == 2) {
            const float* A32 = (const float*)Av;
            #pragma unroll
            for (int i = 0; i < 2; ++i) {
                int s = i * 512 + t;
                int row = s >> 3;
                int kcd = (s & 7) ^ (row & 7);
                int k = ke + kcd * 4;
                int grow = m0 + row; if (grow >= VOCAB) grow = VOCAB - 1;
                const float* g = (k <= 296) ? (A32 + (size_t)grow * WD + k) : zbuf;
                async_load16(g, Asm + i * 8192 + w * 1024);
            }
        } else {
            int row = t >> 2;
            int kcd = (t & 3) ^ ((row >> 2) & 3);
            const bf16* g;
            if constexpr (AMODE == 1) {
                int sel = ke >> 8;
                int id = (sel & 2) ? ((sel & 1) ? idq.w : idq.z)
                                   : ((sel & 1) ? idq.y : idq.x);
                g = Ab + (size_t)id * 256 + (ke & 255) + kcd * 8;
            } else {
                g = Ab + (size_t)(m0 + row) * As + ke + kcd * 8;
            }
            async_load16(g, Asm + w * 1024);
        }
        #pragma unroll
        for (int i = 0; i < 2; ++i) {
            int s = i * 512 + t;
            int col = s >> 2;
            int kcd = (s & 3) ^ ((col >> 2) & 3);
            async_load16(BT + (size_t)col * Bstr + ke + kcd * 8,
                         Bsm + i * 8192 + w * 1024);
        }
    };

    f32x4 acc[4][4] = {};

    auto compute = [&](int buf) {
        const char* Asm = smem + buf * STAGE;
        const bf16* Bs16 = (const bf16*)(Asm + ASZ);
        bf16x8 af[4], bfr[4];
        if constexpr (AMODE == 2) {
            const float* As32 = (const float*)Asm;
            #pragma unroll
            for (int r = 0; r < 4; ++r) {
                int row = rg * 64 + r * 16 + mi;
                int sl = row * 8 + ((2 * q) ^ (row & 7));
                f32x4 lo = *(const f32x4*)(As32 + sl * 4);
                f32x4 hi = *(const f32x4*)(As32 + (sl ^ 1) * 4);
                union { bf16x8 v; bf16 hh[8]; } u;
                #pragma unroll
                for (int j = 0; j < 4; ++j) u.hh[j] = __float2bfloat16(lo[j]);
                #pragma unroll
                for (int j = 0; j < 4; ++j) u.hh[4 + j] = __float2bfloat16(hi[j]);
                af[r] = u.v;
            }
        } else {
            const bf16* As16 = (const bf16*)Asm;
            #pragma unroll
            for (int r = 0; r < 4; ++r) {
                int row = rg * 64 + r * 16 + mi;
                int slot = row * 4 + (q ^ ((row >> 2) & 3));
                af[r] = *(const bf16x8*)(As16 + slot * 8);
            }
        }
        #pragma unroll
        for (int c = 0; c < 4; ++c) {
            int col = cgr * 64 + c * 16 + mi;
            int slot = col * 4 + (q ^ ((col >> 2) & 3));
            bfr[c] = *(const bf16x8*)(Bs16 + slot * 8);
        }
        #pragma unroll
        for (int r = 0; r < 4; ++r)
            #pragma unroll
            for (int c = 0; c < 4; ++c)
                acc[r][c] = __builtin_amdgcn_mfma_f32_16x16x32_bf16(af[r], bfr[c], acc[r][c], 0, 0, 0);
    };

    const int S = K >> 5;
    if constexpr (AMODE == 2) {
        for (int k0 = 0; k0 < S; ++k0) {
            stage(k0 * 32, 0);
            __syncthreads();
            compute(0);
            __syncthreads();
        }
    } else {
        stage(0, 0);
        if (S > 1) stage(32, 1);
        for (int k0 = 0; k0 < S; ++k0) {
            if (k0 + 1 < S)
                asm volatile("s_waitcnt vmcnt(3)\n\ts_barrier" ::: "memory");
            else
                asm volatile("s_waitcnt vmcnt(0)\n\ts_barrier" ::: "memory");
            if (k0 + 2 < S) stage((k0 + 2) * 32, (k0 + 2) % 3);
            compute(k0 % 3);
        }
    }

    // epilogue: C/D layout col = lane&15, row = (lane>>4)*4 + i
    #pragma unroll
    for (int r = 0; r < 4; ++r) {
        int rowb = m0 + rg * 64 + r * 16 + q * 4;
        #pragma unroll
        for (int c = 0; c < 4; ++c) {
            int col = cgr * 64 + c * 16 + mi;
            float bv = bias[col];
            #pragma unroll
            for (int i = 0; i < 4; ++i) {
                float v = acc[r][c][i] + bv;
                size_t o = (size_t)(rowb + i) * Cs + coff + col;
                if (OUT_F32) ((float*)C)[o] = v;
                else         ((bf16*)C)[o] = __float2bfloat16(v);
            }
        }
    }
}

// ---------- mega2: everything after prep in ONE dispatch ---------------------
// 512 blocks x 512 threads, 73728 B LDS -> exactly 2 blocks/CU = all resident.
// Phases separated by software grid barrier (device-scope atomics).
__global__ __launch_bounds__(512, 4)
void mega2(const float* __restrict__ emb, const int* __restrict__ ids,
           const bf16* __restrict__ w1t, const float* __restrict__ b1,
           const bf16* __restrict__ w2t, const bf16* __restrict__ w2b,
           bf16* __restrict__ w4t, const float* __restrict__ b4,
           const float* __restrict__ zbuf,
           bf16* __restrict__ proj, bf16* __restrict__ h,
           bf16* __restrict__ t1, bf16* __restrict__ t2, bf16* __restrict__ t3,
           float* __restrict__ out, int* __restrict__ bar)
{
    __shared__ char smem[73728];
    const int blk = blockIdx.x;
    int* cnt = bar;
    int* gen = bar + 4;

    // P0: W4T products (blocks 0..7) || proj = emb@W1+b1 (blocks 8..401)
    if (blk < 8) {
        int j = blk >> 1, s = blk & 1;
        tile_gemm<0, false>(smem, w2t + 256 * (j >> 1), nullptr,
                            w2b + 65536 * (j & 1), 256, zbuf,
                            w4t, 1024, 256 * j, 256, 512, s * 128, nullptr);
    } else if (blk < 402) {
        tile_gemm<2, false>(smem, emb, nullptr, w1t, KP1, b1,
                            proj, 256, 0, KP1, WD, (blk - 8) * 128, zbuf);
    }
    gbar(cnt, gen, 512);

    // P1: main — h = concat4(proj[ids4]) @ W4 + b4  (all 512 blocks)
    tile_gemm<1, false>(smem, proj, ids, w4t, 1024, b4,
                        h, 256, 0, 1024, 256, blk * 128, nullptr);
    gbar(cnt, gen, 512);

    // P2: t1 = view(h,[16384x1024]) @ W4 + b4
    if (blk < 128)
        tile_gemm<0, false>(smem, h, nullptr, w4t, 1024, b4,
                            t1, 256, 0, 1024, 1024, blk * 128, nullptr);
    gbar(cnt, gen, 512);

    // P3: t2 = view(t1,[4096x1024]) @ W4 + b4
    if (blk < 32)
        tile_gemm<0, false>(smem, t1, nullptr, w4t, 1024, b4,
                            t2, 256, 0, 1024, 1024, blk * 128, nullptr);
    gbar(cnt, gen, 512);

    // P4: t3 = view(t2,[1024x1024]) @ W4 + b4
    if (blk < 8)
        tile_gemm<0, false>(smem, t2, nullptr, w4t, 1024, b4,
                            t3, 256, 0, 1024, 1024, blk * 128, nullptr);
    gbar(cnt, gen, 512);

    // P5: roots = view(t3,[256x1024]) @ W4 + b4, fp32 -> out
    if (blk < 2)
        tile_gemm<0, true>(smem, t3, nullptr, w4t, 1024, b4,
                           out, 256, 0, 1024, 1024, blk * 128, nullptr);
}

extern "C" void kernel_launch(void* const* d_in, const int* in_sizes, int n_in,
                              void* d_out, int out_size, void* d_ws, size_t ws_size,
                              hipStream_t stream) {
    const int*   ids = (const int*)d_in[0];
    const float* emb = (const float*)d_in[1];
    const float* W1  = (const float*)d_in[2];
    const float* b1  = (const float*)d_in[3];
    const float* W2  = (const float*)d_in[4];
    const float* b2  = (const float*)d_in[5];
    (void)in_sizes; (void)n_in; (void)out_size; (void)ws_size;

    char* ws = (char*)d_ws;
    size_t off = 0;
    float* zbuf = (float*)(ws + off); off += 1024;
    float* b4   = (float*)(ws + off); off += 1024;
    int*   bar  = (int*)(ws + off);   off += 1024;
    bf16* w1t = (bf16*)(ws + off); off += (size_t)256 * KP1 * 2;     // 160 KB
    bf16* w2t = (bf16*)(ws + off); off += (size_t)256 * 512 * 2;     // 256 KB
    bf16* w2b = (bf16*)(ws + off); off += (size_t)512 * 256 * 2;     // 256 KB
    bf16* w4t = (bf16*)(ws + off); off += (size_t)256 * 1024 * 2;    // 512 KB
    bf16* proj = (bf16*)(ws + off); off += (size_t)MP * 256 * 2;     // 25.8 MB
    bf16* h  = (bf16*)(ws + off); off += (size_t)65536 * 256 * 2;    // 33.5 MB
    bf16* t1 = (bf16*)(ws + off); off += (size_t)16384 * 256 * 2;    // 8.4 MB
    bf16* t2 = (bf16*)(ws + off); off += (size_t)4096 * 256 * 2;     // 2.1 MB
    bf16* t3 = (bf16*)(ws + off); off += (size_t)1024 * 256 * 2;     // 0.5 MB
    (void)off;

    // D1: weights + b4 + zeros + barrier-state zero
    prep_w<<<1345, 256, 0, stream>>>(W1, W2, b2, w1t, w2t, w2b, b4, zbuf, bar);

    // D2: everything else, grid-barrier separated
    mega2<<<512, 512, 0, stream>>>(emb, ids, w1t, b1, w2t, w2b, w4t, b4, zbuf,
                                   proj, h, t1, t2, t3, (float*)d_out, bar);
}

// Round 14
// 311.909 us; speedup vs baseline: 1.6889x; 1.6889x over previous
//
#include <hip/hip_runtime.h>
#include <hip/hip_bf16.h>
#include <stdint.h>

#define VOCAB 50257
#define WD 300
#define KP1 320              // word dim padded to mult of 32
#define MP 50432             // vocab rows padded: 394*128

using bf16 = __hip_bfloat16;
typedef __attribute__((ext_vector_type(4))) float f32x4;
typedef __attribute__((ext_vector_type(8))) short bf16x8;

// async global->LDS, 16B per lane; LDS dest = wave-uniform base + lane*16
__device__ __forceinline__ void async_load16(const void* g, void* l) {
    __builtin_amdgcn_global_load_lds(
        (const __attribute__((address_space(1))) uint32_t*)(uintptr_t)g,
        (__attribute__((address_space(3))) uint32_t*)l, 16, 0, 0);
}

// ---------- prep: w1t = W1^T bf16 [256x320]; w2t = W2^T bf16 [256x512];
//                  w2b = W2 cast bf16 [512x256]; b4 = b2@(A+B)+b2; zbuf zeros
__global__ void prep_w(const float* __restrict__ W1, const float* __restrict__ W2,
                       const float* __restrict__ b2,
                       bf16* __restrict__ w1t, bf16* __restrict__ w2t,
                       bf16* __restrict__ w2b, float* __restrict__ b4,
                       float* __restrict__ zbuf) {
    if (blockIdx.x == 1344) {           // bias block: b4 = b2@(A+B) + b2
        __shared__ float b2s[256];
        int n = threadIdx.x;
        b2s[n] = b2[n];
        zbuf[n] = 0.0f;
        __syncthreads();
        float acc = b2s[n];
        #pragma unroll 8
        for (int k = 0; k < 256; ++k)
            acc += b2s[k] * (W2[k * 256 + n] + W2[(k + 256) * 256 + n]);
        b4[n] = acc;
        return;
    }
    int idx = blockIdx.x * 256 + threadIdx.x;
    if (idx < 256 * KP1) {                              // w1t = W1^T (zero-pad)
        int n = idx / KP1;
        int k = idx - n * KP1;
        w1t[idx] = __float2bfloat16(k < WD ? W1[k * 256 + n] : 0.0f);
    } else if (idx < 256 * KP1 + 131072) {              // w2t = W2^T
        int j = idx - 256 * KP1;
        int n = j >> 9, k = j & 511;
        w2t[j] = __float2bfloat16(W2[k * 256 + n]);
    } else {                                            // w2b = cast(W2)
        int j = idx - 256 * KP1 - 131072;
        w2b[j] = __float2bfloat16(W2[j]);
    }
}

// ---------- unified 128-row x 256-col tile (8 waves: 2 rg x 4 cgr) -----------
// AMODE 0: A bf16, row stride As elems; 3-stage PIPE (verified R8/R10/R12)
// AMODE 1: A row r = concat4(proj[ids4[m0+r]]), K = 1024; 3-stage PIPE
// AMODE 2: A fp32 rows stride WD (emb, clamped); single-stage 2-barrier
// DUAL: additionally write transposed copy C2[col*Cs2 + coff2 + row] (bf16)
template <int AMODE, bool OUT_F32, bool DUAL = false>
__device__ __forceinline__ void tile_gemm(
    char* smem, const void* Av, const int* ids,
    const bf16* BT, int Bstr, const float* bias,
    void* C, int Cs, int coff, int K, int As, int m0,
    const float* zbuf, bf16* C2 = nullptr, int Cs2 = 0, int coff2 = 0)
{
    constexpr int ASZ = (AMODE == 2) ? 16384 : 8192;
    constexpr int BSZ = 16384, STAGE = ASZ + BSZ;

    const int t = threadIdx.x, w = t >> 6, lane = t & 63;
    const int rg = w >> 2, cgr = w & 3, mi = lane & 15, q = lane >> 4;
    const bf16* Ab = (const bf16*)Av;

    int4 idq = {0, 0, 0, 0};
    if constexpr (AMODE == 1) idq = ((const int4*)ids)[m0 + (t >> 2)];

    auto stage = [&](int ke, int buf) {
        char* Asm = smem + buf * STAGE;
        char* Bsm = Asm + ASZ;
        if constexpr (AMODE == 2) {
            const float* A32 = (const float*)Av;
            #pragma unroll
            for (int i = 0; i < 2; ++i) {
                int s = i * 512 + t;
                int row = s >> 3;
                int kcd = (s & 7) ^ (row & 7);
                int k = ke + kcd * 4;
                int grow = m0 + row; if (grow >= VOCAB) grow = VOCAB - 1;
                const float* g = (k <= 296) ? (A32 + (size_t)grow * WD + k) : zbuf;
                async_load16(g, Asm + i * 8192 + w * 1024);
            }
        } else {
            int row = t >> 2;
            int kcd = (t & 3) ^ ((row >> 2) & 3);
            const bf16* g;
            if constexpr (AMODE == 1) {
                int sel = ke >> 8;
                int id = (sel & 2) ? ((sel & 1) ? idq.w : idq.z)
                                   : ((sel & 1) ? idq.y : idq.x);
                g = Ab + (size_t)id * 256 + (ke & 255) + kcd * 8;
            } else {
                g = Ab + (size_t)(m0 + row) * As + ke + kcd * 8;
            }
            async_load16(g, Asm + w * 1024);
        }
        #pragma unroll
        for (int i = 0; i < 2; ++i) {
            int s = i * 512 + t;
            int col = s >> 2;
            int kcd = (s & 3) ^ ((col >> 2) & 3);
            async_load16(BT + (size_t)col * Bstr + ke + kcd * 8,
                         Bsm + i * 8192 + w * 1024);
        }
    };

    f32x4 acc[4][4] = {};

    auto compute = [&](int buf) {
        const char* Asm = smem + buf * STAGE;
        const bf16* Bs16 = (const bf16*)(Asm + ASZ);
        bf16x8 af[4], bfr[4];
        if constexpr (AMODE == 2) {
            const float* As32 = (const float*)Asm;
            #pragma unroll
            for (int r = 0; r < 4; ++r) {
                int row = rg * 64 + r * 16 + mi;
                int sl = row * 8 + ((2 * q) ^ (row & 7));
                f32x4 lo = *(const f32x4*)(As32 + sl * 4);
                f32x4 hi = *(const f32x4*)(As32 + (sl ^ 1) * 4);
                union { bf16x8 v; bf16 hh[8]; } u;
                #pragma unroll
                for (int j = 0; j < 4; ++j) u.hh[j] = __float2bfloat16(lo[j]);
                #pragma unroll
                for (int j = 0; j < 4; ++j) u.hh[4 + j] = __float2bfloat16(hi[j]);
                af[r] = u.v;
            }
        } else {
            const bf16* As16 = (const bf16*)Asm;
            #pragma unroll
            for (int r = 0; r < 4; ++r) {
                int row = rg * 64 + r * 16 + mi;
                int slot = row * 4 + (q ^ ((row >> 2) & 3));
                af[r] = *(const bf16x8*)(As16 + slot * 8);
            }
        }
        #pragma unroll
        for (int c = 0; c < 4; ++c) {
            int col = cgr * 64 + c * 16 + mi;
            int slot = col * 4 + (q ^ ((col >> 2) & 3));
            bfr[c] = *(const bf16x8*)(Bs16 + slot * 8);
        }
        #pragma unroll
        for (int r = 0; r < 4; ++r)
            #pragma unroll
            for (int c = 0; c < 4; ++c)
                acc[r][c] = __builtin_amdgcn_mfma_f32_16x16x32_bf16(af[r], bfr[c], acc[r][c], 0, 0, 0);
    };

    const int S = K >> 5;
    if constexpr (AMODE == 2) {
        for (int k0 = 0; k0 < S; ++k0) {
            stage(k0 * 32, 0);
            __syncthreads();
            compute(0);
            __syncthreads();
        }
    } else {
        stage(0, 0);
        if (S > 1) stage(32, 1);
        for (int k0 = 0; k0 < S; ++k0) {
            if (k0 + 1 < S)
                asm volatile("s_waitcnt vmcnt(3)\n\ts_barrier" ::: "memory");
            else
                asm volatile("s_waitcnt vmcnt(0)\n\ts_barrier" ::: "memory");
            if (k0 + 2 < S) stage((k0 + 2) * 32, (k0 + 2) % 3);
            compute(k0 % 3);
        }
    }

    // epilogue: C/D layout col = lane&15, row = (lane>>4)*4 + i
    #pragma unroll
    for (int r = 0; r < 4; ++r) {
        int rowb = m0 + rg * 64 + r * 16 + q * 4;
        #pragma unroll
        for (int c = 0; c < 4; ++c) {
            int col = cgr * 64 + c * 16 + mi;
            float bv = bias[col];
            #pragma unroll
            for (int i = 0; i < 4; ++i) {
                float v = acc[r][c][i] + bv;
                size_t o = (size_t)(rowb + i) * Cs + coff + col;
                if (OUT_F32) ((float*)C)[o] = v;
                else         ((bf16*)C)[o] = __float2bfloat16(v);
                if constexpr (DUAL)
                    C2[(size_t)col * Cs2 + coff2 + (rowb + i)] = __float2bfloat16(v);
            }
        }
    }
}

// ---------- D2: W4T (blocks 0..7, dual-write w4t+w4r) || proj (8..401) -------
__global__ __launch_bounds__(512)
void combo(const float* __restrict__ emb, const bf16* __restrict__ w1t,
           const float* __restrict__ b1, const bf16* __restrict__ w2t,
           const bf16* __restrict__ w2b, bf16* __restrict__ w4t,
           bf16* __restrict__ w4r, bf16* __restrict__ proj,
           const float* __restrict__ zbuf) {
    __shared__ char smem[73728];
    int blk = blockIdx.x;
    if (blk < 8) {
        int j = blk >> 1, s = blk & 1;
        tile_gemm<0, false, true>(smem, w2t + 256 * (j >> 1), nullptr,
                                  w2b + 65536 * (j & 1), 256, zbuf,
                                  w4t, 1024, 256 * j, 256, 512, s * 128, nullptr,
                                  w4r, 256, 65536 * j);
    } else {
        tile_gemm<2, false>(smem, emb, nullptr, w1t, KP1, b1,
                            proj, 256, 0, KP1, WD, (blk - 8) * 128, zbuf);
    }
}

// ---------- D3: w16 products (blocks 0..31) + b16 (block 32) + main (33..544) -
// W16_i = W4_s @ W4_j (i = 4j+s). Stored as BT: w16t[col*4096 + 256i + r].
// Computed transposed: D[n,r] = sum_m W4_j[m,n]*W4_s[r,m]:
//   A[n,m] = w4t[n*1024 + 256j + m] (As=1024), BT[r,m] = w4r[(256s+r)*256+m] (Bstr=256)
__global__ __launch_bounds__(512)
void d3K(const bf16* __restrict__ proj, const int* __restrict__ ids,
         const bf16* __restrict__ w4t, const bf16* __restrict__ w4r,
         const float* __restrict__ b4, const float* __restrict__ zbuf,
         bf16* __restrict__ h, bf16* __restrict__ w16t, float* __restrict__ b16) {
    __shared__ char smem[73728];
    int blk = blockIdx.x;
    if (blk < 32) {
        int i = blk >> 1, half = blk & 1;
        int j = i >> 2, s = i & 3;
        tile_gemm<0, false>(smem, w4t + 256 * j, nullptr,
                            w4r + 65536 * s, 256, zbuf,
                            w16t, 4096, 256 * i, 256, 1024, half * 128, nullptr);
    } else if (blk == 32) {
        // b16[n] = sum_r b4[r] * sum_j W4[256j+r, n] + b4[n]
        __shared__ float b4s[256];
        int t = threadIdx.x;
        if (t < 256) b4s[t] = b4[t];
        __syncthreads();
        if (t < 256) {
            float acc = b4s[t];
            const bf16* wrow = w4t + (size_t)t * 1024;
            #pragma unroll 4
            for (int r = 0; r < 256; ++r) {
                float s4 = __bfloat162float(wrow[r]) + __bfloat162float(wrow[256 + r])
                         + __bfloat162float(wrow[512 + r]) + __bfloat162float(wrow[768 + r]);
                acc += b4s[r] * s4;
            }
            b16[t] = acc;
        }
    } else {
        tile_gemm<1, false>(smem, proj, ids, w4t, 1024, b4,
                            h, 256, 0, 1024, 256, (blk - 33) * 128, nullptr);
    }
}

// ---------- D4: tailA — levels 2-5: t4 = view(h,[4096x4096]) @ W16 + b16 -----
__global__ __launch_bounds__(512)
void tailA(const bf16* __restrict__ h, const bf16* __restrict__ w16t,
           const float* __restrict__ b16, bf16* __restrict__ t4) {
    __shared__ char smem[73728];
    tile_gemm<0, false>(smem, h, nullptr, w16t, 4096, b16,
                        t4, 256, 0, 4096, 4096, blockIdx.x * 128, nullptr);
}

// ---------- D5: tailB — levels 6-9: roots = view(t4,[256x4096]) @ W16 + b16 --
__global__ __launch_bounds__(512)
void tailB(const bf16* __restrict__ t4, const bf16* __restrict__ w16t,
           const float* __restrict__ b16, float* __restrict__ out) {
    __shared__ char smem[73728];
    tile_gemm<0, true>(smem, t4, nullptr, w16t, 4096, b16,
                       out, 256, 0, 4096, 4096, blockIdx.x * 128, nullptr);
}

extern "C" void kernel_launch(void* const* d_in, const int* in_sizes, int n_in,
                              void* d_out, int out_size, void* d_ws, size_t ws_size,
                              hipStream_t stream) {
    const int*   ids = (const int*)d_in[0];
    const float* emb = (const float*)d_in[1];
    const float* W1  = (const float*)d_in[2];
    const float* b1  = (const float*)d_in[3];
    const float* W2  = (const float*)d_in[4];
    const float* b2  = (const float*)d_in[5];
    (void)in_sizes; (void)n_in; (void)out_size; (void)ws_size;

    char* ws = (char*)d_ws;
    size_t off = 0;
    float* zbuf = (float*)(ws + off); off += 1024;
    float* b4   = (float*)(ws + off); off += 1024;
    float* b16  = (float*)(ws + off); off += 1024;
    bf16* w1t  = (bf16*)(ws + off); off += (size_t)256 * KP1 * 2;    // 160 KB
    bf16* w2t  = (bf16*)(ws + off); off += (size_t)256 * 512 * 2;    // 256 KB
    bf16* w2b  = (bf16*)(ws + off); off += (size_t)512 * 256 * 2;    // 256 KB
    bf16* w4t  = (bf16*)(ws + off); off += (size_t)256 * 1024 * 2;   // 512 KB
    bf16* w4r  = (bf16*)(ws + off); off += (size_t)1024 * 256 * 2;   // 512 KB
    bf16* w16t = (bf16*)(ws + off); off += (size_t)256 * 4096 * 2;   // 2 MB
    bf16* proj = (bf16*)(ws + off); off += (size_t)MP * 256 * 2;     // 25.8 MB
    bf16* h    = (bf16*)(ws + off); off += (size_t)65536 * 256 * 2;  // 33.5 MB
    bf16* t4   = (bf16*)(ws + off); off += (size_t)4096 * 256 * 2;   // 2.1 MB
    (void)off;

    // D1: weight casts/transposes + b4 + zeros
    prep_w<<<1345, 256, 0, stream>>>(W1, W2, b2, w1t, w2t, w2b, b4, zbuf);

    // D2: W4T (dual-write) || proj
    combo<<<402, 512, 0, stream>>>(emb, w1t, b1, w2t, w2b, w4t, w4r, proj, zbuf);

    // D3: w16 + b16 (33 low blocks) || main gather-GEMM (512 blocks)
    d3K<<<545, 512, 0, stream>>>(proj, ids, w4t, w4r, b4, zbuf, h, w16t, b16);

    // D4: levels 2-5 in one GEMM
    tailA<<<32, 512, 0, stream>>>(h, w16t, b16, t4);

    // D5: levels 6-9 -> fp32 roots
    tailB<<<2, 512, 0, stream>>>(t4, w16t, b16, (float*)d_out);
}

// Round 15
// 228.179 us; speedup vs baseline: 2.3086x; 1.3670x over previous
//
#include <hip/hip_runtime.h>
#include <hip/hip_bf16.h>
#include <stdint.h>

#define VOCAB 50257
#define WD 300
#define KP1 320              // word dim padded to mult of 32
#define MP 50432             // vocab rows padded: 394*128

using bf16 = __hip_bfloat16;
typedef __attribute__((ext_vector_type(4))) float f32x4;
typedef __attribute__((ext_vector_type(8))) short bf16x8;

// async global->LDS, 16B per lane; LDS dest = wave-uniform base + lane*16
__device__ __forceinline__ void async_load16(const void* g, void* l) {
    __builtin_amdgcn_global_load_lds(
        (const __attribute__((address_space(1))) uint32_t*)(uintptr_t)g,
        (__attribute__((address_space(3))) uint32_t*)l, 16, 0, 0);
}

// ---------- prep: w1t = W1^T bf16 [256x320]; w2t = W2^T bf16 [256x512];
//                  w2b = W2 cast bf16 [512x256]; b4 = b2@(A+B)+b2; zbuf zeros
__global__ void prep_w(const float* __restrict__ W1, const float* __restrict__ W2,
                       const float* __restrict__ b2,
                       bf16* __restrict__ w1t, bf16* __restrict__ w2t,
                       bf16* __restrict__ w2b, float* __restrict__ b4,
                       float* __restrict__ zbuf) {
    if (blockIdx.x == 1344) {           // bias block: b4 = b2@(A+B) + b2
        __shared__ float b2s[256];
        int n = threadIdx.x;
        b2s[n] = b2[n];
        zbuf[n] = 0.0f;
        __syncthreads();
        float acc = b2s[n];
        #pragma unroll 8
        for (int k = 0; k < 256; ++k)
            acc += b2s[k] * (W2[k * 256 + n] + W2[(k + 256) * 256 + n]);
        b4[n] = acc;
        return;
    }
    int idx = blockIdx.x * 256 + threadIdx.x;
    if (idx < 256 * KP1) {                              // w1t = W1^T (zero-pad)
        int n = idx / KP1;
        int k = idx - n * KP1;
        w1t[idx] = __float2bfloat16(k < WD ? W1[k * 256 + n] : 0.0f);
    } else if (idx < 256 * KP1 + 131072) {              // w2t = W2^T
        int j = idx - 256 * KP1;
        int n = j >> 9, k = j & 511;
        w2t[j] = __float2bfloat16(W2[k * 256 + n]);
    } else {                                            // w2b = cast(W2)
        int j = idx - 256 * KP1 - 131072;
        w2b[j] = __float2bfloat16(W2[j]);
    }
}

// ---------- unified 128-row x 256-col tile (8 waves: 2 rg x 4 cgr) -----------
// AMODE 0: A bf16, row stride As elems; 3-stage PIPE (verified R8/R10/R12)
// AMODE 1: A row r = concat4(proj[ids4[m0+r]]), K = 1024; 3-stage PIPE
// AMODE 2: A fp32 rows stride WD (emb, clamped); single-stage 2-barrier
template <int AMODE, bool OUT_F32>
__device__ __forceinline__ void tile_gemm(
    char* smem, const void* Av, const int* ids,
    const bf16* BT, int Bstr, const float* bias,
    void* C, int Cs, int coff, int K, int As, int m0,
    const float* zbuf)
{
    constexpr int ASZ = (AMODE == 2) ? 16384 : 8192;
    constexpr int BSZ = 16384, STAGE = ASZ + BSZ;

    const int t = threadIdx.x, w = t >> 6, lane = t & 63;
    const int rg = w >> 2, cgr = w & 3, mi = lane & 15, q = lane >> 4;
    const bf16* Ab = (const bf16*)Av;

    int4 idq = {0, 0, 0, 0};
    if constexpr (AMODE == 1) idq = ((const int4*)ids)[m0 + (t >> 2)];

    auto stage = [&](int ke, int buf) {
        char* Asm = smem + buf * STAGE;
        char* Bsm = Asm + ASZ;
        if constexpr (AMODE == 2) {
            const float* A32 = (const float*)Av;
            #pragma unroll
            for (int i = 0; i < 2; ++i) {
                int s = i * 512 + t;
                int row = s >> 3;
                int kcd = (s & 7) ^ (row & 7);
                int k = ke + kcd * 4;
                int grow = m0 + row; if (grow >= VOCAB) grow = VOCAB - 1;
                const float* g = (k <= 296) ? (A32 + (size_t)grow * WD + k) : zbuf;
                async_load16(g, Asm + i * 8192 + w * 1024);
            }
        } else {
            int row = t >> 2;
            int kcd = (t & 3) ^ ((row >> 2) & 3);
            const bf16* g;
            if constexpr (AMODE == 1) {
                int sel = ke >> 8;
                int id = (sel & 2) ? ((sel & 1) ? idq.w : idq.z)
                                   : ((sel & 1) ? idq.y : idq.x);
                g = Ab + (size_t)id * 256 + (ke & 255) + kcd * 8;
            } else {
                g = Ab + (size_t)(m0 + row) * As + ke + kcd * 8;
            }
            async_load16(g, Asm + w * 1024);
        }
        #pragma unroll
        for (int i = 0; i < 2; ++i) {
            int s = i * 512 + t;
            int col = s >> 2;
            int kcd = (s & 3) ^ ((col >> 2) & 3);
            async_load16(BT + (size_t)col * Bstr + ke + kcd * 8,
                         Bsm + i * 8192 + w * 1024);
        }
    };

    f32x4 acc[4][4] = {};

    auto compute = [&](int buf) {
        const char* Asm = smem + buf * STAGE;
        const bf16* Bs16 = (const bf16*)(Asm + ASZ);
        bf16x8 af[4], bfr[4];
        if constexpr (AMODE == 2) {
            const float* As32 = (const float*)Asm;
            #pragma unroll
            for (int r = 0; r < 4; ++r) {
                int row = rg * 64 + r * 16 + mi;
                int sl = row * 8 + ((2 * q) ^ (row & 7));
                f32x4 lo = *(const f32x4*)(As32 + sl * 4);
                f32x4 hi = *(const f32x4*)(As32 + (sl ^ 1) * 4);
                union { bf16x8 v; bf16 hh[8]; } u;
                #pragma unroll
                for (int j = 0; j < 4; ++j) u.hh[j] = __float2bfloat16(lo[j]);
                #pragma unroll
                for (int j = 0; j < 4; ++j) u.hh[4 + j] = __float2bfloat16(hi[j]);
                af[r] = u.v;
            }
        } else {
            const bf16* As16 = (const bf16*)Asm;
            #pragma unroll
            for (int r = 0; r < 4; ++r) {
                int row = rg * 64 + r * 16 + mi;
                int slot = row * 4 + (q ^ ((row >> 2) & 3));
                af[r] = *(const bf16x8*)(As16 + slot * 8);
            }
        }
        #pragma unroll
        for (int c = 0; c < 4; ++c) {
            int col = cgr * 64 + c * 16 + mi;
            int slot = col * 4 + (q ^ ((col >> 2) & 3));
            bfr[c] = *(const bf16x8*)(Bs16 + slot * 8);
        }
        #pragma unroll
        for (int r = 0; r < 4; ++r)
            #pragma unroll
            for (int c = 0; c < 4; ++c)
                acc[r][c] = __builtin_amdgcn_mfma_f32_16x16x32_bf16(af[r], bfr[c], acc[r][c], 0, 0, 0);
    };

    const int S = K >> 5;
    if constexpr (AMODE == 2) {
        for (int k0 = 0; k0 < S; ++k0) {
            stage(k0 * 32, 0);
            __syncthreads();
            compute(0);
            __syncthreads();
        }
    } else {
        stage(0, 0);
        if (S > 1) stage(32, 1);
        for (int k0 = 0; k0 < S; ++k0) {
            if (k0 + 1 < S)
                asm volatile("s_waitcnt vmcnt(3)\n\ts_barrier" ::: "memory");
            else
                asm volatile("s_waitcnt vmcnt(0)\n\ts_barrier" ::: "memory");
            if (k0 + 2 < S) stage((k0 + 2) * 32, (k0 + 2) % 3);
            compute(k0 % 3);
        }
    }

    // epilogue: C/D layout col = lane&15, row = (lane>>4)*4 + i
    #pragma unroll
    for (int r = 0; r < 4; ++r) {
        int rowb = m0 + rg * 64 + r * 16 + q * 4;
        #pragma unroll
        for (int c = 0; c < 4; ++c) {
            int col = cgr * 64 + c * 16 + mi;
            float bv = bias[col];
            #pragma unroll
            for (int i = 0; i < 4; ++i) {
                float v = acc[r][c][i] + bv;
                size_t o = (size_t)(rowb + i) * Cs + coff + col;
                if (OUT_F32) ((float*)C)[o] = v;
                else         ((bf16*)C)[o] = __float2bfloat16(v);
            }
        }
    }
}

// ---------- D2: W4T (blocks 0..7) || proj (blocks 8..401) --------------------
__global__ __launch_bounds__(512)
void combo(const float* __restrict__ emb, const bf16* __restrict__ w1t,
           const float* __restrict__ b1, const bf16* __restrict__ w2t,
           const bf16* __restrict__ w2b, bf16* __restrict__ w4t,
           bf16* __restrict__ proj, const float* __restrict__ zbuf) {
    __shared__ char smem[73728];
    int blk = blockIdx.x;
    if (blk < 8) {
        int j = blk >> 1, s = blk & 1;
        tile_gemm<0, false>(smem, w2t + 256 * (j >> 1), nullptr,
                            w2b + 65536 * (j & 1), 256, zbuf,
                            w4t, 1024, 256 * j, 256, 512, s * 128, nullptr);
    } else {
        tile_gemm<2, false>(smem, emb, nullptr, w1t, KP1, b1,
                            proj, 256, 0, KP1, WD, (blk - 8) * 128, zbuf);
    }
}

// ---------- D3: main — h = concat4(proj[ids4]) @ W4 + b4 ---------------------
__global__ __launch_bounds__(512)
void mainK(const bf16* __restrict__ proj, const int* __restrict__ ids,
           const bf16* __restrict__ w4t, const float* __restrict__ b4,
           bf16* __restrict__ h) {
    __shared__ char smem[73728];
    tile_gemm<1, false>(smem, proj, ids, w4t, 1024, b4,
                        h, 256, 0, 1024, 256, blockIdx.x * 128, nullptr);
}

// ---------- D4: treeK — levels 2-9 block-local (128 blocks) ------------------
// Phase A: t1 tile [128x256] = view(h,[16384x1024]) rows [128b..) (verified
//   PIPE) -> LDS Ht. Level chain is self-contained per tile:
// Phase B: t2 rows [32b..+32) = view(Ht,[32x1024]) @ W4 -> Ht2 (fat staging)
// Phase C: t3 rows [8b..+8)   = view(Ht2,[8x1024]) @ W4 -> Ht3
// Phase D: roots [2b..+2)     = view(Ht3,[2x1024]) @ W4 -> fp32 out
__global__ __launch_bounds__(512)
void treeK(const bf16* __restrict__ h, const bf16* __restrict__ w4t,
           const float* __restrict__ b4, float* __restrict__ out) {
    constexpr int ASZ = 8192, BSZ = 16384, STAGE = ASZ + BSZ;
    __shared__ char smem[3 * STAGE];   // 72 KB (phase A pipeline; B-D fat bufs)
    __shared__ bf16 Ht[128 * 256];     // 64 KB
    __shared__ bf16 Ht2[32 * 256];     // 16 KB
    __shared__ bf16 Ht3[8 * 256];      // 4 KB   (total 156 KB)

    const int t = threadIdx.x, w = t >> 6, lane = t & 63;
    const int rg = w >> 2, cgr = w & 3, mi = lane & 15, q = lane >> 4;
    const int b = blockIdx.x;
    const int m0 = b * 128;

    // ---- phase A: t1 tile [128 x 256] (verified PIPE) -> Ht ----
    {
        auto stageA = [&](int ke, int buf) {
            char* Asm = smem + buf * STAGE;
            char* Bsm = Asm + ASZ;
            int row = t >> 2;
            int kcd = (t & 3) ^ ((row >> 2) & 3);
            async_load16(h + (size_t)(m0 + row) * 1024 + ke + kcd * 8, Asm + w * 1024);
            #pragma unroll
            for (int i = 0; i < 2; ++i) {
                int s = i * 512 + t;
                int col = s >> 2;
                int kcd2 = (s & 3) ^ ((col >> 2) & 3);
                async_load16(w4t + (size_t)col * 1024 + ke + kcd2 * 8,
                             Bsm + i * 8192 + w * 1024);
            }
        };
        f32x4 acc[4][4] = {};
        stageA(0, 0); stageA(32, 1);
        for (int k0i = 0; k0i < 32; ++k0i) {
            if (k0i + 1 < 32)
                asm volatile("s_waitcnt vmcnt(3)\n\ts_barrier" ::: "memory");
            else
                asm volatile("s_waitcnt vmcnt(0)\n\ts_barrier" ::: "memory");
            if (k0i + 2 < 32) stageA((k0i + 2) * 32, (k0i + 2) % 3);
            const bf16* As16 = (const bf16*)(smem + (k0i % 3) * STAGE);
            const bf16* Bs16 = (const bf16*)(smem + (k0i % 3) * STAGE + ASZ);
            bf16x8 af[4], bfr[4];
            #pragma unroll
            for (int r = 0; r < 4; ++r) {
                int row = rg * 64 + r * 16 + mi;
                int slot = row * 4 + (q ^ ((row >> 2) & 3));
                af[r] = *(const bf16x8*)(As16 + slot * 8);
            }
            #pragma unroll
            for (int c = 0; c < 4; ++c) {
                int col = cgr * 64 + c * 16 + mi;
                int slot = col * 4 + (q ^ ((col >> 2) & 3));
                bfr[c] = *(const bf16x8*)(Bs16 + slot * 8);
            }
            #pragma unroll
            for (int r = 0; r < 4; ++r)
                #pragma unroll
                for (int c = 0; c < 4; ++c)
                    acc[r][c] = __builtin_amdgcn_mfma_f32_16x16x32_bf16(af[r], bfr[c], acc[r][c], 0, 0, 0);
        }
        // epilogue -> Ht: slot(row,col) = (row*32 + ((col>>3) ^ (row&31)))*8 + (col&7)
        #pragma unroll
        for (int r = 0; r < 4; ++r) {
            int rowb = rg * 64 + r * 16 + q * 4;
            #pragma unroll
            for (int c = 0; c < 4; ++c) {
                int col = cgr * 64 + c * 16 + mi;
                float bv = b4[col];
                int chunk = col >> 3;
                #pragma unroll
                for (int i = 0; i < 4; ++i) {
                    int row = rowb + i;
                    Ht[(row * 32 + (chunk ^ (row & 31))) * 8 + (col & 7)] =
                        __float2bfloat16(acc[r][c][i] + bv);
                }
            }
        }
    }
    __syncthreads();

    // fat B staging: [256 cols x 64 k] = 32 KB into smem + buf*32768
    auto stageF = [&](int ke, int buf) {
        char* Bb = smem + buf * 32768;
        #pragma unroll
        for (int sub = 0; sub < 2; ++sub)
            #pragma unroll
            for (int i = 0; i < 2; ++i) {
                int s = i * 512 + t;
                int col = s >> 2;
                int kcd = (s & 3) ^ ((col >> 2) & 3);
                async_load16(w4t + (size_t)col * 1024 + ke + sub * 32 + kcd * 8,
                             Bb + sub * 16384 + i * 8192 + w * 1024);
            }
    };

    // ---- phase B: 32 rows = view(Ht,[32x1024]) @ W4 + b4 -> Ht2 (16 rounds) ----
    {
        f32x4 acc2[4] = {};
        stageF(0, 0);
        for (int r = 0; r < 16; ++r) {
            if (r + 1 < 16) {
                stageF((r + 1) * 64, (r + 1) & 1);
                asm volatile("s_waitcnt vmcnt(4)\n\ts_barrier" ::: "memory");
            } else {
                asm volatile("s_waitcnt vmcnt(0)\n\ts_barrier" ::: "memory");
            }
            const bf16* Bb = (const bf16*)(smem + (r & 1) * 32768);
            #pragma unroll
            for (int sub = 0; sub < 2; ++sub) {
                int k0 = r * 64 + sub * 32;
                int n = rg * 16 + mi;
                int r2 = 4 * n + (k0 >> 8);
                int kc = ((k0 & 255) >> 3) + q;
                bf16x8 a = *(const bf16x8*)(Ht + (r2 * 32 + (kc ^ (r2 & 31))) * 8);
                #pragma unroll
                for (int c = 0; c < 4; ++c) {
                    int col = cgr * 64 + c * 16 + mi;
                    int slot = col * 4 + (q ^ ((col >> 2) & 3));
                    bf16x8 bb = *(const bf16x8*)(Bb + sub * 8192 + slot * 8);
                    acc2[c] = __builtin_amdgcn_mfma_f32_16x16x32_bf16(a, bb, acc2[c], 0, 0, 0);
                }
            }
            __syncthreads();
        }
        #pragma unroll
        for (int c = 0; c < 4; ++c) {
            int col = cgr * 64 + c * 16 + mi;
            float bv = b4[col];
            int chunk = col >> 3;
            #pragma unroll
            for (int i = 0; i < 4; ++i) {
                int row = rg * 16 + q * 4 + i;      // 0..31
                Ht2[(row * 32 + (chunk ^ (row & 31))) * 8 + (col & 7)] =
                    __float2bfloat16(acc2[c][i] + bv);
            }
        }
    }
    __syncthreads();

    // ---- phase C: 8 rows = view(Ht2,[8x1024]) @ W4 + b4 -> Ht3 (16 rounds) ----
    {
        f32x4 acc3[4] = {};
        stageF(0, 0);
        for (int r = 0; r < 16; ++r) {
            if (r + 1 < 16) {
                stageF((r + 1) * 64, (r + 1) & 1);
                asm volatile("s_waitcnt vmcnt(4)\n\ts_barrier" ::: "memory");
            } else {
                asm volatile("s_waitcnt vmcnt(0)\n\ts_barrier" ::: "memory");
            }
            const bf16* Bb = (const bf16*)(smem + (r & 1) * 32768);
            #pragma unroll
            for (int sub = 0; sub < 2; ++sub) {
                int k0 = r * 64 + sub * 32;
                int r3 = (4 * mi + (k0 >> 8)) & 31;     // valid mi<8; rest unused
                int kc = ((k0 & 255) >> 3) + q;
                bf16x8 a = *(const bf16x8*)(Ht2 + (r3 * 32 + (kc ^ (r3 & 31))) * 8);
                #pragma unroll
                for (int c = 0; c < 4; ++c) {
                    int col = cgr * 64 + c * 16 + mi;
                    int slot = col * 4 + (q ^ ((col >> 2) & 3));
                    bf16x8 bb = *(const bf16x8*)(Bb + sub * 8192 + slot * 8);
                    acc3[c] = __builtin_amdgcn_mfma_f32_16x16x32_bf16(a, bb, acc3[c], 0, 0, 0);
                }
            }
            __syncthreads();
        }
        if (rg == 0 && q < 2) {                         // rows 0..7 valid
            #pragma unroll
            for (int c = 0; c < 4; ++c) {
                int col = cgr * 64 + c * 16 + mi;
                float bv = b4[col];
                #pragma unroll
                for (int i = 0; i < 4; ++i)
                    Ht3[(q * 4 + i) * 256 + col] = __float2bfloat16(acc3[c][i] + bv);
            }
        }
    }
    __syncthreads();

    // ---- phase D: 2 roots = view(Ht3,[2x1024]) @ W4 + b4 -> out (16 rounds) ----
    {
        f32x4 acc4[4] = {};
        stageF(0, 0);
        for (int r = 0; r < 16; ++r) {
            if (r + 1 < 16) {
                stageF((r + 1) * 64, (r + 1) & 1);
                asm volatile("s_waitcnt vmcnt(4)\n\ts_barrier" ::: "memory");
            } else {
                asm volatile("s_waitcnt vmcnt(0)\n\ts_barrier" ::: "memory");
            }
            const bf16* Bb = (const bf16*)(smem + (r & 1) * 32768);
            #pragma unroll
            for (int sub = 0; sub < 2; ++sub) {
                int k0 = r * 64 + sub * 32;
                int r4 = (4 * (mi & 1) + (k0 >> 8)) & 7;   // valid mi<2; rest unused
                bf16x8 a = *(const bf16x8*)(Ht3 + r4 * 256 + (k0 & 255) + q * 8);
                #pragma unroll
                for (int c = 0; c < 4; ++c) {
                    int col = cgr * 64 + c * 16 + mi;
                    int slot = col * 4 + (q ^ ((col >> 2) & 3));
                    bf16x8 bb = *(const bf16x8*)(Bb + sub * 8192 + slot * 8);
                    acc4[c] = __builtin_amdgcn_mfma_f32_16x16x32_bf16(a, bb, acc4[c], 0, 0, 0);
                }
            }
            __syncthreads();
        }
        if (rg == 0 && q == 0) {                        // rows 0..1 valid (i<2)
            #pragma unroll
            for (int c = 0; c < 4; ++c) {
                int col = cgr * 64 + c * 16 + mi;
                float bv = b4[col];
                #pragma unroll
                for (int i = 0; i < 2; ++i)
                    out[(size_t)(b * 2 + i) * 256 + col] = acc4[c][i] + bv;
            }
        }
    }
}

extern "C" void kernel_launch(void* const* d_in, const int* in_sizes, int n_in,
                              void* d_out, int out_size, void* d_ws, size_t ws_size,
                              hipStream_t stream) {
    const int*   ids = (const int*)d_in[0];
    const float* emb = (const float*)d_in[1];
    const float* W1  = (const float*)d_in[2];
    const float* b1  = (const float*)d_in[3];
    const float* W2  = (const float*)d_in[4];
    const float* b2  = (const float*)d_in[5];
    (void)in_sizes; (void)n_in; (void)out_size; (void)ws_size;

    char* ws = (char*)d_ws;
    size_t off = 0;
    float* zbuf = (float*)(ws + off); off += 1024;
    float* b4   = (float*)(ws + off); off += 1024;
    bf16* w1t = (bf16*)(ws + off); off += (size_t)256 * KP1 * 2;     // 160 KB
    bf16* w2t = (bf16*)(ws + off); off += (size_t)256 * 512 * 2;     // 256 KB
    bf16* w2b = (bf16*)(ws + off); off += (size_t)512 * 256 * 2;     // 256 KB
    bf16* w4t = (bf16*)(ws + off); off += (size_t)256 * 1024 * 2;    // 512 KB
    bf16* proj = (bf16*)(ws + off); off += (size_t)MP * 256 * 2;     // 25.8 MB
    bf16* h  = (bf16*)(ws + off); off += (size_t)65536 * 256 * 2;    // 33.5 MB
    (void)off;

    // D1: weight casts/transposes + b4 + zeros
    prep_w<<<1345, 256, 0, stream>>>(W1, W2, b2, w1t, w2t, w2b, b4, zbuf);

    // D2: W4T products (blocks 0..7) || proj = emb@W1+b1 (blocks 8..401)
    combo<<<402, 512, 0, stream>>>(emb, w1t, b1, w2t, w2b, w4t, proj, zbuf);

    // D3: main — leaves + levels 0-1 fused (PIPE)
    mainK<<<512, 512, 0, stream>>>(proj, ids, w4t, b4, h);

    // D4: levels 2-9 block-local: t1 tile (PIPE) + 3 fat phases, one dispatch
    treeK<<<128, 512, 0, stream>>>(h, w4t, b4, (float*)d_out);
}

// Round 16
// 222.084 us; speedup vs baseline: 2.3720x; 1.0274x over previous
//
#include <hip/hip_runtime.h>
#include <hip/hip_bf16.h>
#include <stdint.h>

#define VOCAB 50257
#define WD 300
#define KP1 320              // word dim padded to mult of 32
#define MP 50432             // vocab rows padded: 394*128

using bf16 = __hip_bfloat16;
typedef __attribute__((ext_vector_type(4))) float f32x4;
typedef __attribute__((ext_vector_type(8))) short bf16x8;

// async global->LDS, 16B per lane; LDS dest = wave-uniform base + lane*16
__device__ __forceinline__ void async_load16(const void* g, void* l) {
    __builtin_amdgcn_global_load_lds(
        (const __attribute__((address_space(1))) uint32_t*)(uintptr_t)g,
        (__attribute__((address_space(3))) uint32_t*)l, 16, 0, 0);
}

// ---------- prep: w1t = W1^T bf16 [256x320]; w2t = W2^T bf16 [256x512];
//                  w2b = W2 cast bf16 [512x256]; b4 = b2@(A+B)+b2; zbuf zeros
__global__ void prep_w(const float* __restrict__ W1, const float* __restrict__ W2,
                       const float* __restrict__ b2,
                       bf16* __restrict__ w1t, bf16* __restrict__ w2t,
                       bf16* __restrict__ w2b, float* __restrict__ b4,
                       float* __restrict__ zbuf) {
    if (blockIdx.x == 1344) {           // bias block: b4 = b2@(A+B) + b2
        __shared__ float b2s[256];
        int n = threadIdx.x;
        b2s[n] = b2[n];
        zbuf[n] = 0.0f;
        __syncthreads();
        float acc = b2s[n];
        #pragma unroll 8
        for (int k = 0; k < 256; ++k)
            acc += b2s[k] * (W2[k * 256 + n] + W2[(k + 256) * 256 + n]);
        b4[n] = acc;
        return;
    }
    int idx = blockIdx.x * 256 + threadIdx.x;
    if (idx < 256 * KP1) {                              // w1t = W1^T (zero-pad)
        int n = idx / KP1;
        int k = idx - n * KP1;
        w1t[idx] = __float2bfloat16(k < WD ? W1[k * 256 + n] : 0.0f);
    } else if (idx < 256 * KP1 + 131072) {              // w2t = W2^T
        int j = idx - 256 * KP1;
        int n = j >> 9, k = j & 511;
        w2t[j] = __float2bfloat16(W2[k * 256 + n]);
    } else {                                            // w2b = cast(W2)
        int j = idx - 256 * KP1 - 131072;
        w2b[j] = __float2bfloat16(W2[j]);
    }
}

// ---------- unified 128-row x 256-col tile (8 waves: 2 rg x 4 cgr) -----------
// AMODE 0: A bf16, row stride As elems; 3-stage PIPE (verified R8/R10/R12)
// AMODE 1: A row r = concat4(proj[ids4[m0+r]]), K = 1024; 3-stage PIPE
// AMODE 2: A fp32 rows stride WD (emb, clamped); 2-stage PIPE w/ raw barriers
template <int AMODE, bool OUT_F32>
__device__ __forceinline__ void tile_gemm(
    char* smem, const void* Av, const int* ids,
    const bf16* BT, int Bstr, const float* bias,
    void* C, int Cs, int coff, int K, int As, int m0,
    const float* zbuf)
{
    constexpr int ASZ = (AMODE == 2) ? 16384 : 8192;
    constexpr int BSZ = 16384, STAGE = ASZ + BSZ;

    const int t = threadIdx.x, w = t >> 6, lane = t & 63;
    const int rg = w >> 2, cgr = w & 3, mi = lane & 15, q = lane >> 4;
    const bf16* Ab = (const bf16*)Av;

    int4 idq = {0, 0, 0, 0};
    if constexpr (AMODE == 1) idq = ((const int4*)ids)[m0 + (t >> 2)];

    auto stage = [&](int ke, int buf) {
        char* Asm = smem + buf * STAGE;
        char* Bsm = Asm + ASZ;
        if constexpr (AMODE == 2) {
            const float* A32 = (const float*)Av;
            #pragma unroll
            for (int i = 0; i < 2; ++i) {
                int s = i * 512 + t;
                int row = s >> 3;
                int kcd = (s & 7) ^ (row & 7);
                int k = ke + kcd * 4;
                int grow = m0 + row; if (grow >= VOCAB) grow = VOCAB - 1;
                const float* g = (k <= 296) ? (A32 + (size_t)grow * WD + k) : zbuf;
                async_load16(g, Asm + i * 8192 + w * 1024);
            }
        } else {
            int row = t >> 2;
            int kcd = (t & 3) ^ ((row >> 2) & 3);
            const bf16* g;
            if constexpr (AMODE == 1) {
                int sel = ke >> 8;
                int id = (sel & 2) ? ((sel & 1) ? idq.w : idq.z)
                                   : ((sel & 1) ? idq.y : idq.x);
                g = Ab + (size_t)id * 256 + (ke & 255) + kcd * 8;
            } else {
                g = Ab + (size_t)(m0 + row) * As + ke + kcd * 8;
            }
            async_load16(g, Asm + w * 1024);
        }
        #pragma unroll
        for (int i = 0; i < 2; ++i) {
            int s = i * 512 + t;
            int col = s >> 2;
            int kcd = (s & 3) ^ ((col >> 2) & 3);
            async_load16(BT + (size_t)col * Bstr + ke + kcd * 8,
                         Bsm + i * 8192 + w * 1024);
        }
    };

    f32x4 acc[4][4] = {};

    auto compute = [&](int buf) {
        const char* Asm = smem + buf * STAGE;
        const bf16* Bs16 = (const bf16*)(Asm + ASZ);
        bf16x8 af[4], bfr[4];
        if constexpr (AMODE == 2) {
            const float* As32 = (const float*)Asm;
            #pragma unroll
            for (int r = 0; r < 4; ++r) {
                int row = rg * 64 + r * 16 + mi;
                int sl = row * 8 + ((2 * q) ^ (row & 7));
                f32x4 lo = *(const f32x4*)(As32 + sl * 4);
                f32x4 hi = *(const f32x4*)(As32 + (sl ^ 1) * 4);
                union { bf16x8 v; bf16 hh[8]; } u;
                #pragma unroll
                for (int j = 0; j < 4; ++j) u.hh[j] = __float2bfloat16(lo[j]);
                #pragma unroll
                for (int j = 0; j < 4; ++j) u.hh[4 + j] = __float2bfloat16(hi[j]);
                af[r] = u.v;
            }
        } else {
            const bf16* As16 = (const bf16*)Asm;
            #pragma unroll
            for (int r = 0; r < 4; ++r) {
                int row = rg * 64 + r * 16 + mi;
                int slot = row * 4 + (q ^ ((row >> 2) & 3));
                af[r] = *(const bf16x8*)(As16 + slot * 8);
            }
        }
        #pragma unroll
        for (int c = 0; c < 4; ++c) {
            int col = cgr * 64 + c * 16 + mi;
            int slot = col * 4 + (q ^ ((col >> 2) & 3));
            bfr[c] = *(const bf16x8*)(Bs16 + slot * 8);
        }
        #pragma unroll
        for (int r = 0; r < 4; ++r)
            #pragma unroll
            for (int c = 0; c < 4; ++c)
                acc[r][c] = __builtin_amdgcn_mfma_f32_16x16x32_bf16(af[r], bfr[c], acc[r][c], 0, 0, 0);
    };

    const int S = K >> 5;
    if constexpr (AMODE == 2) {
        // 2-stage PIPE with raw barriers (no compiler vmcnt(0) drain)
        stage(0, 0);
        for (int k0 = 0; k0 < S; ++k0) {
            if (k0 + 1 < S) {
                stage((k0 + 1) * 32, (k0 + 1) & 1);
                asm volatile("s_waitcnt vmcnt(4)\n\ts_barrier" ::: "memory");
            } else {
                asm volatile("s_waitcnt vmcnt(0)\n\ts_barrier" ::: "memory");
            }
            compute(k0 & 1);
            asm volatile("s_waitcnt lgkmcnt(0)\n\ts_barrier" ::: "memory");
        }
    } else {
        stage(0, 0);
        if (S > 1) stage(32, 1);
        for (int k0 = 0; k0 < S; ++k0) {
            if (k0 + 1 < S)
                asm volatile("s_waitcnt vmcnt(3)\n\ts_barrier" ::: "memory");
            else
                asm volatile("s_waitcnt vmcnt(0)\n\ts_barrier" ::: "memory");
            if (k0 + 2 < S) stage((k0 + 2) * 32, (k0 + 2) % 3);
            compute(k0 % 3);
        }
    }

    // epilogue: C/D layout col = lane&15, row = (lane>>4)*4 + i
    #pragma unroll
    for (int r = 0; r < 4; ++r) {
        int rowb = m0 + rg * 64 + r * 16 + q * 4;
        #pragma unroll
        for (int c = 0; c < 4; ++c) {
            int col = cgr * 64 + c * 16 + mi;
            float bv = bias[col];
            #pragma unroll
            for (int i = 0; i < 4; ++i) {
                float v = acc[r][c][i] + bv;
                size_t o = (size_t)(rowb + i) * Cs + coff + col;
                if (OUT_F32) ((float*)C)[o] = v;
                else         ((bf16*)C)[o] = __float2bfloat16(v);
            }
        }
    }
}

// ---------- D2: W4T (blocks 0..7) || proj (blocks 8..401) --------------------
__global__ __launch_bounds__(512)
void combo(const float* __restrict__ emb, const bf16* __restrict__ w1t,
           const float* __restrict__ b1, const bf16* __restrict__ w2t,
           const bf16* __restrict__ w2b, bf16* __restrict__ w4t,
           bf16* __restrict__ proj, const float* __restrict__ zbuf) {
    __shared__ char smem[73728];
    int blk = blockIdx.x;
    if (blk < 8) {
        int j = blk >> 1, s = blk & 1;
        tile_gemm<0, false>(smem, w2t + 256 * (j >> 1), nullptr,
                            w2b + 65536 * (j & 1), 256, zbuf,
                            w4t, 1024, 256 * j, 256, 512, s * 128, nullptr);
    } else {
        tile_gemm<2, false>(smem, emb, nullptr, w1t, KP1, b1,
                            proj, 256, 0, KP1, WD, (blk - 8) * 128, zbuf);
    }
}

// ---------- D3: main — h = concat4(proj[ids4]) @ W4 + b4 ---------------------
__global__ __launch_bounds__(512)
void mainK(const bf16* __restrict__ proj, const int* __restrict__ ids,
           const bf16* __restrict__ w4t, const float* __restrict__ b4,
           bf16* __restrict__ h) {
    __shared__ char smem[73728];
    tile_gemm<1, false>(smem, proj, ids, w4t, 1024, b4,
                        h, 256, 0, 1024, 256, blockIdx.x * 128, nullptr);
}

// ---------- D4: treeK — levels 2-9 block-local (128 blocks) ------------------
__global__ __launch_bounds__(512)
void treeK(const bf16* __restrict__ h, const bf16* __restrict__ w4t,
           const float* __restrict__ b4, float* __restrict__ out) {
    constexpr int ASZ = 8192, BSZ = 16384, STAGE = ASZ + BSZ;
    __shared__ char smem[3 * STAGE];   // 72 KB
    __shared__ bf16 Ht[128 * 256];     // 64 KB
    __shared__ bf16 Ht2[32 * 256];     // 16 KB
    __shared__ bf16 Ht3[8 * 256];      // 4 KB   (total 156 KB)

    const int t = threadIdx.x, w = t >> 6, lane = t & 63;
    const int rg = w >> 2, cgr = w & 3, mi = lane & 15, q = lane >> 4;
    const int b = blockIdx.x;
    const int m0 = b * 128;

    // ---- phase A: t1 tile [128 x 256] (verified PIPE) -> Ht ----
    {
        auto stageA = [&](int ke, int buf) {
            char* Asm = smem + buf * STAGE;
            char* Bsm = Asm + ASZ;
            int row = t >> 2;
            int kcd = (t & 3) ^ ((row >> 2) & 3);
            async_load16(h + (size_t)(m0 + row) * 1024 + ke + kcd * 8, Asm + w * 1024);
            #pragma unroll
            for (int i = 0; i < 2; ++i) {
                int s = i * 512 + t;
                int col = s >> 2;
                int kcd2 = (s & 3) ^ ((col >> 2) & 3);
                async_load16(w4t + (size_t)col * 1024 + ke + kcd2 * 8,
                             Bsm + i * 8192 + w * 1024);
            }
        };
        f32x4 acc[4][4] = {};
        stageA(0, 0); stageA(32, 1);
        for (int k0i = 0; k0i < 32; ++k0i) {
            if (k0i + 1 < 32)
                asm volatile("s_waitcnt vmcnt(3)\n\ts_barrier" ::: "memory");
            else
                asm volatile("s_waitcnt vmcnt(0)\n\ts_barrier" ::: "memory");
            if (k0i + 2 < 32) stageA((k0i + 2) * 32, (k0i + 2) % 3);
            const bf16* As16 = (const bf16*)(smem + (k0i % 3) * STAGE);
            const bf16* Bs16 = (const bf16*)(smem + (k0i % 3) * STAGE + ASZ);
            bf16x8 af[4], bfr[4];
            #pragma unroll
            for (int r = 0; r < 4; ++r) {
                int row = rg * 64 + r * 16 + mi;
                int slot = row * 4 + (q ^ ((row >> 2) & 3));
                af[r] = *(const bf16x8*)(As16 + slot * 8);
            }
            #pragma unroll
            for (int c = 0; c < 4; ++c) {
                int col = cgr * 64 + c * 16 + mi;
                int slot = col * 4 + (q ^ ((col >> 2) & 3));
                bfr[c] = *(const bf16x8*)(Bs16 + slot * 8);
            }
            #pragma unroll
            for (int r = 0; r < 4; ++r)
                #pragma unroll
                for (int c = 0; c < 4; ++c)
                    acc[r][c] = __builtin_amdgcn_mfma_f32_16x16x32_bf16(af[r], bfr[c], acc[r][c], 0, 0, 0);
        }
        #pragma unroll
        for (int r = 0; r < 4; ++r) {
            int rowb = rg * 64 + r * 16 + q * 4;
            #pragma unroll
            for (int c = 0; c < 4; ++c) {
                int col = cgr * 64 + c * 16 + mi;
                float bv = b4[col];
                int chunk = col >> 3;
                #pragma unroll
                for (int i = 0; i < 4; ++i) {
                    int row = rowb + i;
                    Ht[(row * 32 + (chunk ^ (row & 31))) * 8 + (col & 7)] =
                        __float2bfloat16(acc[r][c][i] + bv);
                }
            }
        }
    }
    __syncthreads();

    // fat B staging: [256 cols x 64 k] = 32 KB into smem + buf*32768
    auto stageF = [&](int ke, int buf) {
        char* Bb = smem + buf * 32768;
        #pragma unroll
        for (int sub = 0; sub < 2; ++sub)
            #pragma unroll
            for (int i = 0; i < 2; ++i) {
                int s = i * 512 + t;
                int col = s >> 2;
                int kcd = (s & 3) ^ ((col >> 2) & 3);
                async_load16(w4t + (size_t)col * 1024 + ke + sub * 32 + kcd * 8,
                             Bb + sub * 16384 + i * 8192 + w * 1024);
            }
    };

    // ---- phase B: 32 rows -> Ht2 (16 rounds, raw trailing barrier) ----
    {
        f32x4 acc2[4] = {};
        stageF(0, 0);
        for (int r = 0; r < 16; ++r) {
            if (r + 1 < 16) {
                stageF((r + 1) * 64, (r + 1) & 1);
                asm volatile("s_waitcnt vmcnt(4)\n\ts_barrier" ::: "memory");
            } else {
                asm volatile("s_waitcnt vmcnt(0)\n\ts_barrier" ::: "memory");
            }
            const bf16* Bb = (const bf16*)(smem + (r & 1) * 32768);
            #pragma unroll
            for (int sub = 0; sub < 2; ++sub) {
                int k0 = r * 64 + sub * 32;
                int n = rg * 16 + mi;
                int r2 = 4 * n + (k0 >> 8);
                int kc = ((k0 & 255) >> 3) + q;
                bf16x8 a = *(const bf16x8*)(Ht + (r2 * 32 + (kc ^ (r2 & 31))) * 8);
                #pragma unroll
                for (int c = 0; c < 4; ++c) {
                    int col = cgr * 64 + c * 16 + mi;
                    int slot = col * 4 + (q ^ ((col >> 2) & 3));
                    bf16x8 bb = *(const bf16x8*)(Bb + sub * 8192 + slot * 8);
                    acc2[c] = __builtin_amdgcn_mfma_f32_16x16x32_bf16(a, bb, acc2[c], 0, 0, 0);
                }
            }
            asm volatile("s_waitcnt lgkmcnt(0)\n\ts_barrier" ::: "memory");
        }
        #pragma unroll
        for (int c = 0; c < 4; ++c) {
            int col = cgr * 64 + c * 16 + mi;
            float bv = b4[col];
            int chunk = col >> 3;
            #pragma unroll
            for (int i = 0; i < 4; ++i) {
                int row = rg * 16 + q * 4 + i;
                Ht2[(row * 32 + (chunk ^ (row & 31))) * 8 + (col & 7)] =
                    __float2bfloat16(acc2[c][i] + bv);
            }
        }
    }
    __syncthreads();

    // ---- phase C: 8 rows -> Ht3 (16 rounds, raw trailing barrier) ----
    {
        f32x4 acc3[4] = {};
        stageF(0, 0);
        for (int r = 0; r < 16; ++r) {
            if (r + 1 < 16) {
                stageF((r + 1) * 64, (r + 1) & 1);
                asm volatile("s_waitcnt vmcnt(4)\n\ts_barrier" ::: "memory");
            } else {
                asm volatile("s_waitcnt vmcnt(0)\n\ts_barrier" ::: "memory");
            }
            const bf16* Bb = (const bf16*)(smem + (r & 1) * 32768);
            #pragma unroll
            for (int sub = 0; sub < 2; ++sub) {
                int k0 = r * 64 + sub * 32;
                int r3 = (4 * mi + (k0 >> 8)) & 31;
                int kc = ((k0 & 255) >> 3) + q;
                bf16x8 a = *(const bf16x8*)(Ht2 + (r3 * 32 + (kc ^ (r3 & 31))) * 8);
                #pragma unroll
                for (int c = 0; c < 4; ++c) {
                    int col = cgr * 64 + c * 16 + mi;
                    int slot = col * 4 + (q ^ ((col >> 2) & 3));
                    bf16x8 bb = *(const bf16x8*)(Bb + sub * 8192 + slot * 8);
                    acc3[c] = __builtin_amdgcn_mfma_f32_16x16x32_bf16(a, bb, acc3[c], 0, 0, 0);
                }
            }
            asm volatile("s_waitcnt lgkmcnt(0)\n\ts_barrier" ::: "memory");
        }
        if (rg == 0 && q < 2) {
            #pragma unroll
            for (int c = 0; c < 4; ++c) {
                int col = cgr * 64 + c * 16 + mi;
                float bv = b4[col];
                #pragma unroll
                for (int i = 0; i < 4; ++i)
                    Ht3[(q * 4 + i) * 256 + col] = __float2bfloat16(acc3[c][i] + bv);
            }
        }
    }
    __syncthreads();

    // ---- phase D: 2 roots -> out (16 rounds, raw trailing barrier) ----
    {
        f32x4 acc4[4] = {};
        stageF(0, 0);
        for (int r = 0; r < 16; ++r) {
            if (r + 1 < 16) {
                stageF((r + 1) * 64, (r + 1) & 1);
                asm volatile("s_waitcnt vmcnt(4)\n\ts_barrier" ::: "memory");
            } else {
                asm volatile("s_waitcnt vmcnt(0)\n\ts_barrier" ::: "memory");
            }
            const bf16* Bb = (const bf16*)(smem + (r & 1) * 32768);
            #pragma unroll
            for (int sub = 0; sub < 2; ++sub) {
                int k0 = r * 64 + sub * 32;
                int r4 = (4 * (mi & 1) + (k0 >> 8)) & 7;
                bf16x8 a = *(const bf16x8*)(Ht3 + r4 * 256 + (k0 & 255) + q * 8);
                #pragma unroll
                for (int c = 0; c < 4; ++c) {
                    int col = cgr * 64 + c * 16 + mi;
                    int slot = col * 4 + (q ^ ((col >> 2) & 3));
                    bf16x8 bb = *(const bf16x8*)(Bb + sub * 8192 + slot * 8);
                    acc4[c] = __builtin_amdgcn_mfma_f32_16x16x32_bf16(a, bb, acc4[c], 0, 0, 0);
                }
            }
            asm volatile("s_waitcnt lgkmcnt(0)\n\ts_barrier" ::: "memory");
        }
        if (rg == 0 && q == 0) {
            #pragma unroll
            for (int c = 0; c < 4; ++c) {
                int col = cgr * 64 + c * 16 + mi;
                float bv = b4[col];
                #pragma unroll
                for (int i = 0; i < 2; ++i)
                    out[(size_t)(b * 2 + i) * 256 + col] = acc4[c][i] + bv;
            }
        }
    }
}

extern "C" void kernel_launch(void* const* d_in, const int* in_sizes, int n_in,
                              void* d_out, int out_size, void* d_ws, size_t ws_size,
                              hipStream_t stream) {
    const int*   ids = (const int*)d_in[0];
    const float* emb = (const float*)d_in[1];
    const float* W1  = (const float*)d_in[2];
    const float* b1  = (const float*)d_in[3];
    const float* W2  = (const float*)d_in[4];
    const float* b2  = (const float*)d_in[5];
    (void)in_sizes; (void)n_in; (void)out_size; (void)ws_size;

    char* ws = (char*)d_ws;
    size_t off = 0;
    float* zbuf = (float*)(ws + off); off += 1024;
    float* b4   = (float*)(ws + off); off += 1024;
    bf16* w1t = (bf16*)(ws + off); off += (size_t)256 * KP1 * 2;     // 160 KB
    bf16* w2t = (bf16*)(ws + off); off += (size_t)256 * 512 * 2;     // 256 KB
    bf16* w2b = (bf16*)(ws + off); off += (size_t)512 * 256 * 2;     // 256 KB
    bf16* w4t = (bf16*)(ws + off); off += (size_t)256 * 1024 * 2;    // 512 KB
    bf16* proj = (bf16*)(ws + off); off += (size_t)MP * 256 * 2;     // 25.8 MB
    bf16* h  = (bf16*)(ws + off); off += (size_t)65536 * 256 * 2;    // 33.5 MB
    (void)off;

    // D1: weight casts/transposes + b4 + zeros
    prep_w<<<1345, 256, 0, stream>>>(W1, W2, b2, w1t, w2t, w2b, b4, zbuf);

    // D2: W4T (blocks 0..7) || proj (blocks 8..401, 2-stage PIPE raw barriers)
    combo<<<402, 512, 0, stream>>>(emb, w1t, b1, w2t, w2b, w4t, proj, zbuf);

    // D3: main — leaves + levels 0-1 fused (PIPE)
    mainK<<<512, 512, 0, stream>>>(proj, ids, w4t, b4, h);

    // D4: levels 2-9 block-local: t1 tile (PIPE) + 3 fat phases (raw barriers)
    treeK<<<128, 512, 0, stream>>>(h, w4t, b4, (float*)d_out);
}